// Round 9
// baseline (269.171 us; speedup 1.0000x reference)
//
#include <hip/hip_runtime.h>
#include <math.h>

typedef unsigned short UST;
typedef __attribute__((ext_vector_type(8))) short bf16x8;
typedef __attribute__((ext_vector_type(4))) float f32x4;

#define BB 4
#define LL 1024
#define IND 256
#define DD 512
#define HH 8
#define FFD 2048
#define NT (BB*LL)

__device__ __forceinline__ float bf2f(UST u){ return __uint_as_float(((unsigned)u)<<16); }
__device__ __forceinline__ UST f2bf(float f){
  unsigned u = __float_as_uint(f);
  u += 0x7FFFu + ((u>>16)&1u);
  return (UST)(u>>16);
}
__device__ __forceinline__ float ldF(const void* p, long i, int isf32){
  return isf32 ? ((const float*)p)[i] : bf2f(((const UST*)p)[i]);
}
__device__ __forceinline__ bool ldMask(const void* p, long i, int fm){
  if (fm==0) return ((const int*)p)[i] != 0;
  if (fm==1) return ((const unsigned char*)p)[i] != 0;
  if (fm==2) return ((const UST*)p)[i] != 0;
  return ((const float*)p)[i] != 0.f;
}
__device__ __forceinline__ f32x4 mfma16(bf16x8 a, bf16x8 b, f32x4 c){
  return __builtin_amdgcn_mfma_f32_16x16x32_bf16(a, b, c, 0, 0, 0);
}
__device__ __forceinline__ void gld16(const void* g, void* l){
  __builtin_amdgcn_global_load_lds((const __attribute__((address_space(1))) unsigned int*)g,
                                   (__attribute__((address_space(3))) unsigned int*)l, 16, 0, 0);
}

// ---------------- dtype detection (one wave) ----------------
__global__ void detect_k(int* flags, const UST* xh, const unsigned int* mw){
  int lane = threadIdx.x & 63;
  int e0 = (xh[lane] >> 7) & 0xFF;
  int e1 = (xh[64+lane] >> 7) & 0xFF;
  int f32 = __any((e0 >= 140) || (e1 >= 140)) ? 1 : 0;
  unsigned v = mw[lane];
  int w01   = __all(v <= 1u) ? 1 : 0;
  unsigned lo = v & 0xFFFFu, hi = v >> 16;
  int half  = __all((lo==0u||lo==0x3F80u) && (hi==0u||hi==0x3F80u)) ? 1 : 0;
  int wordF = __all(v==0u || v==0x3F800000u) ? 1 : 0;
  int byteB = __all((v & 0xFEFEFEFEu) == 0u) ? 1 : 0;
  if (lane == 0){
    flags[0] = f32;
    flags[1] = w01 ? 0 : (half ? (wordF ? 3 : 2) : (byteB ? 1 : 0));
  }
}

// ---------------- prep: bias precompute in ATTN-FRAGMENT layout + cvt ----------
// bias2 layout: tile (b,qt,kt) of 64x64 at base ((b*16+qt)*16+kt)*4096 USTs;
// within: w*1024 + (qd*16+l15)*16 + r*4 + ni  -> attn lane reads its 16 values
// as two coalesced b128 loads (lane stride 32B).
struct CvtArgs { const void* src[11]; UST* dst[11]; int n[11]; };
__global__ __launch_bounds__(256) void prep_k(const int* flags, CvtArgs a,
    const void* mask, const void* adj, const void* lsp, UST* biasOut){
  int bid = blockIdx.x;
  int t = threadIdx.x;
  __shared__ UST sTile[1024];
  __shared__ int sAll[4];
  if (bid < BB*LL){
    int fF = flags[0], fM = flags[1];
    int row = bid;
    int i = row & (LL-1);
    long base = (long)row * LL;
    int j0 = t*4;
    bool mv[4];
    if (fM == 0){
      int4 m4 = *(const int4*)((const int*)mask + base + j0);
      mv[0]=m4.x!=0; mv[1]=m4.y!=0; mv[2]=m4.z!=0; mv[3]=m4.w!=0;
    } else {
      #pragma unroll
      for (int k=0;k<4;++k) mv[k] = ldMask(mask, base + j0 + k, fM);
    }
    float a4[4];
    if (fF){
      float4 av = *(const float4*)((const float*)adj + base + j0);
      a4[0]=av.x; a4[1]=av.y; a4[2]=av.z; a4[3]=av.w;
    } else {
      const UST* ap = (const UST*)adj + base + j0;
      #pragma unroll
      for (int k=0;k<4;++k) a4[k] = bf2f(ap[k]);
    }
    int my = (mv[0]&&mv[1]&&mv[2]&&mv[3]) ? 1 : 0;
    int wa = __all(my);
    int w = t >> 6;
    if ((t & 63) == 0) sAll[w] = wa;
    __syncthreads();
    int rowAll = sAll[0] & sAll[1] & sAll[2] & sAll[3];
    float es = expf(ldF(lsp, 0, fF));
    UST o4[4];
    #pragma unroll
    for (int k = 0; k < 4; ++k){
      int j = j0 + k;
      float av = fminf(fmaxf(a4[k], 0.f), 1.f);
      bool eff = mv[k] && !((rowAll != 0) && (j == i));
      o4[k] = f2bf(((eff ? -10000.f : 0.f) + es * av) * 1.44269504f);
    }
    *(int2*)&sTile[j0] = *(const int2*)o4;
    __syncthreads();
    // transpose-gather: thread (kt=t>>4, l15=t&15) packs ni=0..3 for its row
    int kt = t >> 4, l15 = t & 15;
    UST g4[4];
    #pragma unroll
    for (int ni=0; ni<4; ++ni) g4[ni] = sTile[kt*64 + ni*16 + l15];
    int b = row >> 10, rr = row & 1023;
    int qt = rr >> 6, q = rr & 63;
    int w2 = q >> 4, qd = (q >> 2) & 3, r = q & 3;
    long dst = ((long)((b*16 + qt)*16 + kt))*4096 + w2*1024 + (qd*16 + l15)*16 + r*4;
    *(int2*)(biasOut + dst) = *(const int2*)g4;
  } else {
    int cb = bid - BB*LL;
    int ti = cb >> 9, xi = cb & 511;
    int n = a.n[ti];
    long i8 = ((long)xi*256 + t)*8;
    if (i8 >= n) return;
    const void* s = a.src[ti]; UST* d = a.dst[ti];
    if (flags[0]){
      const float4* sf = (const float4*)s;
      float4 a0 = sf[i8>>2], a1 = sf[(i8>>2)+1];
      UST o[8] = { f2bf(a0.x),f2bf(a0.y),f2bf(a0.z),f2bf(a0.w),
                   f2bf(a1.x),f2bf(a1.y),f2bf(a1.z),f2bf(a1.w) };
      *(int4*)(d+i8) = *(const int4*)o;
    } else {
      ((int4*)d)[i8>>3] = ((const int4*)s)[i8>>3];
    }
  }
}

// ---------------- MFMA GEMM: tile TM x TN, BK=64, dbuf prefetch ----------------
template<int TM, int TN, int ACT, int RES, int OUTMODE>
__global__ __launch_bounds__(256) void gemm3_k(const int* flags,
    const UST* __restrict__ A, const UST* __restrict__ Bw, const UST* __restrict__ bias,
    const float* __restrict__ resid, void* Cout, int M, int N, int K, int Ks){
  constexpr int MI = TM/32, NI = TN/32;
  __shared__ UST sA[2][TM*64];
  __shared__ UST sB[2][TN*64];
  int t = threadIdx.x, w = t>>6, lane = t&63, l15 = lane&15, qd = lane>>4;
  int m0 = blockIdx.x*TM, n0 = blockIdx.y*TN;
  int zoff = blockIdx.z * Ks;
  int wm = (w&1)*(TM/2), wn = (w>>1)*(TN/2);
  f32x4 acc[MI][NI];
  #pragma unroll
  for (int mi=0; mi<MI; ++mi)
    #pragma unroll
    for (int ni=0; ni<NI; ++ni){ acc[mi][ni][0]=0;acc[mi][ni][1]=0;acc[mi][ni][2]=0;acc[mi][ni][3]=0; }
  int sRow = lane&7, sCol = (lane>>3)*8;
  const UST* aS = A + (long)(m0 + w*(TM/4) + sRow)*K + sCol + zoff;
  const UST* bS = Bw + (long)(n0 + w*(TN/4) + sRow)*K + sCol + zoff;
  auto stage = [&](int buf, int k0){
    #pragma unroll
    for (int c=0;c<MI;++c) gld16(aS + (long)c*8*K + k0, (char*)&sA[buf][(w*(TM/4)+c*8)*64]);
    #pragma unroll
    for (int c=0;c<NI;++c) gld16(bS + (long)c*8*K + k0, (char*)&sB[buf][(w*(TN/4)+c*8)*64]);
  };
  stage(0, 0);
  for (int k0 = 0; k0 < Ks; k0 += 64){
    int cur = (k0>>6)&1, nxt = cur^1;
    __syncthreads();
    if (k0 + 64 < Ks) stage(nxt, k0+64);
    #pragma unroll
    for (int ks=0; ks<2; ++ks){
      bf16x8 afr[MI], bfr[NI];
      #pragma unroll
      for (int mi=0; mi<MI; ++mi){
        int R = wm + mi*16 + l15;
        afr[mi] = *(const bf16x8*)&sA[cur][(R>>3)*512 + (ks*4+qd)*64 + (R&7)*8];
      }
      #pragma unroll
      for (int ni=0; ni<NI; ++ni){
        int R = wn + ni*16 + l15;
        bfr[ni] = *(const bf16x8*)&sB[cur][(R>>3)*512 + (ks*4+qd)*64 + (R&7)*8];
      }
      #pragma unroll
      for (int mi=0; mi<MI; ++mi)
        #pragma unroll
        for (int ni=0; ni<NI; ++ni)
          acc[mi][ni] = mfma16(afr[mi], bfr[ni], acc[mi][ni]);
    }
  }
  if (OUTMODE == 3){
    float* P = (float*)Cout + (size_t)blockIdx.z * M * N;
    #pragma unroll
    for (int mi=0; mi<MI; ++mi)
      #pragma unroll
      for (int ni=0; ni<NI; ++ni){
        int gc = n0 + wn + ni*16 + l15;
        #pragma unroll
        for (int r=0; r<4; ++r){
          int grow = m0 + wm + mi*16 + qd*4 + r;
          P[(long)grow*N + gc] = acc[mi][ni][r];
        }
      }
    return;
  }
  int outF32 = (OUTMODE==1) || (OUTMODE==2 && flags[0]);
  #pragma unroll
  for (int mi=0; mi<MI; ++mi){
    #pragma unroll
    for (int ni=0; ni<NI; ++ni){
      int gc = n0 + wn + ni*16 + l15;
      float bv = bf2f(bias[gc]);
      #pragma unroll
      for (int r=0; r<4; ++r){
        int grow = m0 + wm + mi*16 + qd*4 + r;
        float c = acc[mi][ni][r] + bv;
        if (ACT) c = 0.5f*c*(1.f+erff(c*0.70710678118654752f));
        long oi = (long)grow*N + gc;
        if (RES) c += resid[oi];
        if (outF32) ((float*)Cout)[oi] = c;
        else ((UST*)Cout)[oi] = f2bf(c);
      }
    }
  }
}

// ---------------- split-K reduce: out = sum(parts) + bias + resid ----------------
__global__ __launch_bounds__(256) void reduce4_k(const int* flags,
    const float* __restrict__ parts, const UST* __restrict__ bias,
    const float* __restrict__ resid, void* __restrict__ dout){
  const long S = (long)NT*DD;
  long e = ((long)blockIdx.x*256 + threadIdx.x)*4;
  float4 a = *(const float4*)(parts + e);
  float4 b = *(const float4*)(parts + S + e);
  float4 c = *(const float4*)(parts + 2*S + e);
  float4 d = *(const float4*)(parts + 3*S + e);
  float4 r = *(const float4*)(resid + e);
  int gc = (int)(e & (DD-1));
  float v[4] = { a.x+b.x+c.x+d.x + bf2f(bias[gc+0]) + r.x,
                 a.y+b.y+c.y+d.y + bf2f(bias[gc+1]) + r.y,
                 a.z+b.z+c.z+d.z + bf2f(bias[gc+2]) + r.z,
                 a.w+b.w+c.w+d.w + bf2f(bias[gc+3]) + r.w };
  if (flags[0]){
    *(float4*)((float*)dout + e) = *(const float4*)v;
  } else {
    UST o4[4] = { f2bf(v[0]), f2bf(v[1]), f2bf(v[2]), f2bf(v[3]) };
    *(int2*)((UST*)dout + e) = *(const int2*)o4;
  }
}

// ---------------- LayerNorm row kernel: fp32 in -> bf16 out ----------------
__global__ __launch_bounds__(256) void ln_k(const int* flags, const float* xin,
    const void* gp, const void* bp, UST* xout){
  int fF = flags[0];
  int row = blockIdx.x, t = threadIdx.x;
  const float* xr = xin + (long)row * DD;
  float v0 = xr[t], v1 = xr[t+256];
  float s = v0+v1, q = v0*v0 + v1*v1;
  #pragma unroll
  for (int off=1; off<64; off<<=1){ s += __shfl_xor(s,off,64); q += __shfl_xor(q,off,64); }
  __shared__ float rs[4], rq[4];
  int w = t>>6;
  if ((t&63)==0){ rs[w]=s; rq[w]=q; }
  __syncthreads();
  float S = rs[0]+rs[1]+rs[2]+rs[3];
  float Q = rq[0]+rq[1]+rq[2]+rq[3];
  float mean = S * (1.f/DD);
  float var  = fmaxf(Q * (1.f/DD) - mean*mean, 0.f);
  float ri = rsqrtf(var + 1e-5f);
  float g0 = ldF(gp, t, fF), b0 = ldF(bp, t, fF);
  float g1 = ldF(gp, t+256, fF), b1 = ldF(bp, t+256, fF);
  xout[(long)row*DD + t]     = f2bf((v0-mean)*ri*g0 + b0);
  xout[(long)row*DD + t+256] = f2bf((v1-mean)*ri*g1 + b1);
}

// ---------------- V transpose: qkv -> vT[b,h,d,token] ----------------
__global__ __launch_bounds__(256) void repack_v(const UST* __restrict__ qkv, UST* __restrict__ vT){
  int id = blockIdx.x;
  int bh = id & 31, qt = id >> 5;
  int b = bh >> 3, h = bh & 7;
  int t = threadIdx.x, w = t >> 6, lane = t & 63;
  int token = qt*64 + lane;
  const UST* src = qkv + ((long)(b*LL + token))*1536 + 1024 + h*64;
  #pragma unroll
  for (int c = 0; c < 2; ++c){
    int ch = w*2 + c;
    union { int4 v; UST u[8]; } uu;
    uu.v = *(const int4*)(src + ch*8);
    #pragma unroll
    for (int i = 0; i < 8; ++i)
      vT[((long)(bh*64 + ch*8 + i))*LL + token] = uu.u[i];
  }
}

// ---------------- flash attention: kt-split x2, bias in registers ------------
// grid 1024: id = qt*64 + slice*32 + h*4 + b (XCD-local per (b,h)).
// Outputs UNNORMALIZED fp32 o-partials + per-row lsum; combine_k normalizes.
__global__ __launch_bounds__(256) void attn_k(const UST* __restrict__ qkv,
    const UST* __restrict__ vT, const UST* __restrict__ bias2,
    float* __restrict__ oPart, float* __restrict__ lsumPart){
  int id = blockIdx.x;
  int b = id & 3, h = (id>>2) & 7, slice = (id>>5) & 1, qt = id >> 6;
  int bh = b*HH + h;
  int q0 = qt*64;
  int t = threadIdx.x, w = t>>6, lane = t&63, l15 = lane&15, qd = lane>>4;
  __shared__ UST sK[2][2][64*32];
  __shared__ UST sV[2][2][64*32];
  __shared__ UST sP[4][16*72];
  UST* myP = &sP[w][0];

  const UST* qrow = qkv + ((long)(b*LL + q0 + w*16 + l15))*1536 + h*64;
  bf16x8 qf0 = *(const bf16x8*)(qrow + qd*8);
  bf16x8 qf1 = *(const bf16x8*)(qrow + 32 + qd*8);

  const UST* kS = qkv + (long)(b*LL + w*16 + (lane&15))*1536 + 512 + h*64 + (lane>>4)*8;
  const UST* vS = vT + (long)(bh*64 + w*16 + (lane&15))*LL + (lane>>4)*8;
  // bias2: per-lane 32B in fragment order, prefetched one iter ahead
  const UST* bP = bias2 + ((long)((b*16 + qt)*16))*4096 + w*1024 + lane*16;

  f32x4 o[4]; float lsum[4];
  #pragma unroll
  for (int i=0;i<4;i++){ o[i][0]=0;o[i][1]=0;o[i][2]=0;o[i][3]=0; lsum[i]=0.f; }
  const float C1 = 0.18033688f;   // 0.125*log2e; bias pre-scaled by log2e

  auto stage = [&](int buf, int k0){
    gld16(kS + (long)k0*1536,      (char*)sK[buf][0] + w*1024);
    gld16(kS + (long)k0*1536 + 32, (char*)sK[buf][1] + w*1024);
    gld16(vS + k0,                 (char*)sV[buf][0] + w*1024);
    gld16(vS + k0 + 32,            (char*)sV[buf][1] + w*1024);
  };
  int ktBase = slice*8;
  stage(0, ktBase*64);
  int4 bc0 = *(const int4*)(bP + (long)ktBase*4096);
  int4 bc1 = *(const int4*)(bP + (long)ktBase*4096 + 8);

  for (int kt = 0; kt < 8; ++kt){
    int cur = kt&1, nxt = cur^1;
    int k0 = (ktBase + kt)*64;
    __syncthreads();
    if (kt < 7) stage(nxt, k0+64);
    int kn = ktBase + (kt < 7 ? kt+1 : 7);
    int4 bn0 = *(const int4*)(bP + (long)kn*4096);
    int4 bn1 = *(const int4*)(bP + (long)kn*4096 + 8);
    f32x4 s4[4];
    #pragma unroll
    for (int i=0;i<4;i++){ s4[i][0]=0;s4[i][1]=0;s4[i][2]=0;s4[i][3]=0; }
    #pragma unroll
    for (int ni=0; ni<4; ++ni){
      bf16x8 kf0 = *(const bf16x8*)&sK[cur][0][ni*512 + qd*128 + l15*8];
      bf16x8 kf1 = *(const bf16x8*)&sK[cur][1][ni*512 + qd*128 + l15*8];
      s4[ni] = mfma16(qf0, kf0, s4[ni]);
      s4[ni] = mfma16(qf1, kf1, s4[ni]);
    }
    union { int4 v; UST u[8]; } B0, B1;
    B0.v = bc0; B1.v = bc1;
    float p[4][4];
    #pragma unroll
    for (int ni=0; ni<4; ++ni){
      #pragma unroll
      for (int r=0; r<4; ++r){
        UST bu = (r < 2) ? B0.u[r*4 + ni] : B1.u[(r&1)*4 + ni];
        p[ni][r] = exp2f(fmaf(s4[ni][r], C1, bf2f(bu)));
      }
    }
    bc0 = bn0; bc1 = bn1;
    #pragma unroll
    for (int r=0; r<4; ++r)
      lsum[r] += (p[0][r]+p[1][r]) + (p[2][r]+p[3][r]);
    #pragma unroll
    for (int ni=0; ni<4; ++ni)
      #pragma unroll
      for (int r=0; r<4; ++r) myP[(qd*4+r)*72 + ni*16 + l15] = f2bf(p[ni][r]);
    bf16x8 pf0 = *(const bf16x8*)&myP[l15*72 + qd*8];
    bf16x8 pf1 = *(const bf16x8*)&myP[l15*72 + 32 + qd*8];
    #pragma unroll
    for (int dn=0; dn<4; ++dn){
      bf16x8 vf0 = *(const bf16x8*)&sV[cur][0][dn*512 + qd*128 + l15*8];
      bf16x8 vf1 = *(const bf16x8*)&sV[cur][1][dn*512 + qd*128 + l15*8];
      o[dn] = mfma16(pf0, vf0, o[dn]);
      o[dn] = mfma16(pf1, vf1, o[dn]);
    }
  }
  // per-row lsum: reduce over the 16 l15 lanes, lane l15==r writes row (qd,r)
  long lsBase = ((long)(slice*32 + bh))*LL + q0 + w*16;
  #pragma unroll
  for (int r=0; r<4; ++r){
    float s = lsum[r];
    #pragma unroll
    for (int off=1; off<16; off<<=1) s += __shfl_xor(s, off, 64);
    if (l15 == r) lsumPart[lsBase + qd*4 + r] = s;
  }
  float* oDst = oPart + (size_t)slice * NT * DD;
  #pragma unroll
  for (int dn=0; dn<4; ++dn){
    #pragma unroll
    for (int r=0; r<4; ++r){
      long oi = ((long)(b*LL + q0 + w*16 + qd*4 + r))*DD + h*64 + dn*16 + l15;
      oDst[oi] = o[dn][r];
    }
  }
}

// ---------------- attention combine: ctx = (o0+o1)/(l0+l1), bf16 ----------------
__global__ __launch_bounds__(256) void combine_k(const float* __restrict__ oPart,
    const float* __restrict__ lsumPart, UST* __restrict__ ctx){
  const long S = (long)NT*DD;
  long e = ((long)blockIdx.x*256 + threadIdx.x)*4;
  float4 a = *(const float4*)(oPart + e);
  float4 c = *(const float4*)(oPart + S + e);
  long row = e >> 9;                 // global token row (b*L + token)
  int col = (int)(e & (DD-1));
  int b = (int)(row >> 10), tok = (int)(row & 1023), h = col >> 6;
  int bh = b*HH + h;
  float l0 = lsumPart[(long)bh*LL + tok];
  float l1 = lsumPart[(long)(32 + bh)*LL + tok];
  float rinv = 1.f / (l0 + l1);
  UST o4[4] = { f2bf((a.x+c.x)*rinv), f2bf((a.y+c.y)*rinv),
                f2bf((a.z+c.z)*rinv), f2bf((a.w+c.w)*rinv) };
  *(int2*)(ctx + e) = *(const int2*)o4;
}

extern "C" void kernel_launch(void* const* d_in, const int* in_sizes, int n_in,
                              void* d_out, int out_size, void* d_ws, size_t ws_size,
                              hipStream_t stream){
  char* ws = (char*)d_ws;
  size_t o = 0;
  auto alloc = [&](size_t b){ size_t r = o; o += (b + 255) & ~(size_t)255; return r; };
  int*   flags = (int*)(ws + alloc(256));
  size_t biasOff = alloc(8UL<<20);
  size_t qkvOff  = alloc(12UL<<20);
  UST* biasC = (UST*)(ws + biasOff);
  UST* qkv   = (UST*)(ws + qkvOff);
  UST* hb    = (UST*)(ws + biasOff);        // aliases biasC+qkv (dead by ffn1)
  UST* vT    = (UST*)(ws + alloc(4UL<<20));
  UST* xbf   = (UST*)(ws + alloc(2UL<<20));
  UST* wfuse = (UST*)(ws + alloc(131072*2));
  UST* bfuse = (UST*)(ws + alloc(1024));
  UST* ipw   = (UST*)(ws + alloc(786432*2));
  UST* ipb   = (UST*)(ws + alloc(3072*2));
  UST* outw  = (UST*)(ws + alloc(262144*2));
  UST* outb  = (UST*)(ws + alloc(1024));
  UST* w1    = (UST*)(ws + alloc(1048576*2));
  UST* b1    = (UST*)(ws + alloc(4096*2));
  UST* w2    = (UST*)(ws + alloc(1048576*2));
  UST* b2    = (UST*)(ws + alloc(1024));
  float* xf  = (float*)(ws + alloc((size_t)NT*DD*4));
  UST* xn    = (UST*)(ws + alloc((size_t)NT*DD*2));
  UST* ctx   = (UST*)(ws + alloc((size_t)NT*DD*2));
  float* x2  = (float*)(ws + alloc((size_t)NT*DD*4));
  float* oPart = (float*)(ws + alloc(2UL*NT*DD*4));     // 16MB attn partials
  float* lsumP = (float*)(ws + alloc(2UL*32*LL*4));     // 256KB lsum partials
  size_t partsOff = alloc(4UL*NT*DD*4);                 // 33.5MB ffn2 split-K
  float* parts = (float*)(ws + partsOff);
  bool doSplit = (o <= ws_size);

  detect_k<<<1, 64, 0, stream>>>(flags, (const UST*)d_in[0], (const unsigned int*)d_in[1]);

  CvtArgs ca;
  const int srcIdx[11] = {0,3,4,5,6,7,8,13,14,15,16};
  UST* dsts[11] = {xbf,wfuse,bfuse,ipw,ipb,outw,outb,w1,b1,w2,b2};
  const int ns[11] = {NT*IND, DD*IND, DD, 3*DD*DD, 3*DD, DD*DD, DD, FFD*DD, FFD, DD*FFD, DD};
  for (int i=0;i<11;i++){ ca.src[i]=d_in[srcIdx[i]]; ca.dst[i]=dsts[i]; ca.n[i]=ns[i]; }
  prep_k<<<BB*LL + 11*512, 256, 0, stream>>>(flags, ca, d_in[1], d_in[2], d_in[17], biasC);

  gemm3_k<64,64,0,0,1><<<dim3(64,8), 256, 0, stream>>>(flags, xbf, wfuse, bfuse, nullptr, xf, NT, DD, IND, IND);
  ln_k<<<NT, 256, 0, stream>>>(flags, xf, d_in[9], d_in[10], xn);
  gemm3_k<64,128,0,0,0><<<dim3(64,12), 256, 0, stream>>>(flags, xn, ipw, ipb, nullptr, qkv, NT, 3*DD, DD, DD);
  repack_v<<<512, 256, 0, stream>>>(qkv, vT);
  attn_k<<<1024, 256, 0, stream>>>(qkv, vT, biasC, oPart, lsumP);
  combine_k<<<(NT*DD)/1024, 256, 0, stream>>>(oPart, lsumP, ctx);
  gemm3_k<64,64,0,1,1><<<dim3(64,8), 256, 0, stream>>>(flags, ctx, outw, outb, xf, x2, NT, DD, DD, DD);
  ln_k<<<NT, 256, 0, stream>>>(flags, x2, d_in[11], d_in[12], xn);
  gemm3_k<128,128,1,0,0><<<dim3(32,16), 256, 0, stream>>>(flags, xn, w1, b1, nullptr, hb, NT, FFD, DD, DD);
  if (doSplit){
    gemm3_k<128,128,0,0,3><<<dim3(32,4,4), 256, 0, stream>>>(flags, hb, w2, b2, nullptr, parts, NT, DD, FFD, FFD/4);
    reduce4_k<<<(NT*DD)/1024, 256, 0, stream>>>(flags, parts, b2, x2, d_out);
  } else {
    gemm3_k<64,64,0,1,2><<<dim3(64,8), 256, 0, stream>>>(flags, hb, w2, b2, x2, d_out, NT, DD, FFD, FFD);
  }
}

// Round 10
// 262.254 us; speedup vs baseline: 1.0264x; 1.0264x over previous
//
#include <hip/hip_runtime.h>
#include <math.h>

typedef unsigned short UST;
typedef __attribute__((ext_vector_type(8))) short bf16x8;
typedef __attribute__((ext_vector_type(4))) float f32x4;

#define BB 4
#define LL 1024
#define IND 256
#define DD 512
#define HH 8
#define FFD 2048
#define NT (BB*LL)

__device__ __forceinline__ float bf2f(UST u){ return __uint_as_float(((unsigned)u)<<16); }
__device__ __forceinline__ UST f2bf(float f){
  unsigned u = __float_as_uint(f);
  u += 0x7FFFu + ((u>>16)&1u);
  return (UST)(u>>16);
}
__device__ __forceinline__ float ldF(const void* p, long i, int isf32){
  return isf32 ? ((const float*)p)[i] : bf2f(((const UST*)p)[i]);
}
__device__ __forceinline__ bool ldMask(const void* p, long i, int fm){
  if (fm==0) return ((const int*)p)[i] != 0;
  if (fm==1) return ((const unsigned char*)p)[i] != 0;
  if (fm==2) return ((const UST*)p)[i] != 0;
  return ((const float*)p)[i] != 0.f;
}
__device__ __forceinline__ f32x4 mfma16(bf16x8 a, bf16x8 b, f32x4 c){
  return __builtin_amdgcn_mfma_f32_16x16x32_bf16(a, b, c, 0, 0, 0);
}
__device__ __forceinline__ void gld16(const void* g, void* l){
  __builtin_amdgcn_global_load_lds((const __attribute__((address_space(1))) unsigned int*)g,
                                   (__attribute__((address_space(3))) unsigned int*)l, 16, 0, 0);
}

// ---------------- prep: self-detect + bias precompute (attn-fragment layout) + cvt ----
// bias2 layout: tile (b,qt,kt) 64x64 at ((b*16+qt)*16+kt)*4096 USTs; within:
// w*1024 + lane*16 + r*4 + ni  -> attn lane reads 16 bias vals as 2 b128 loads.
struct CvtArgs { const void* src[11]; UST* dst[11]; int n[11]; };
__global__ __launch_bounds__(256) void prep_k(int* flags, CvtArgs a,
    const UST* xh, const void* mask, const void* adj, const void* lsp, UST* biasOut){
  int bid = blockIdx.x;
  int t = threadIdx.x;
  __shared__ UST sTile[1024];
  __shared__ int sAll[4];
  __shared__ int sFlags[2];
  // per-block wave-0 dtype detect (L2-cached reads; no cross-block dep)
  if (t < 64){
    int lane = t;
    int e0 = (xh[lane] >> 7) & 0xFF;
    int e1 = (xh[64+lane] >> 7) & 0xFF;
    int f32 = __any((e0 >= 140) || (e1 >= 140)) ? 1 : 0;
    unsigned v = ((const unsigned int*)mask)[lane];
    int w01   = __all(v <= 1u) ? 1 : 0;
    unsigned lo = v & 0xFFFFu, hi = v >> 16;
    int half  = __all((lo==0u||lo==0x3F80u) && (hi==0u||hi==0x3F80u)) ? 1 : 0;
    int wordF = __all(v==0u || v==0x3F800000u) ? 1 : 0;
    int byteB = __all((v & 0xFEFEFEFEu) == 0u) ? 1 : 0;
    if (lane == 0){
      int fm = w01 ? 0 : (half ? (wordF ? 3 : 2) : (byteB ? 1 : 0));
      sFlags[0] = f32; sFlags[1] = fm;
      if (bid == 0){ flags[0] = f32; flags[1] = fm; }
    }
  }
  __syncthreads();
  int fF = sFlags[0], fM = sFlags[1];
  if (bid < BB*LL){
    int row = bid;
    int i = row & (LL-1);
    long base = (long)row * LL;
    int j0 = t*4;
    bool mv[4];
    if (fM == 0){
      int4 m4 = *(const int4*)((const int*)mask + base + j0);
      mv[0]=m4.x!=0; mv[1]=m4.y!=0; mv[2]=m4.z!=0; mv[3]=m4.w!=0;
    } else {
      #pragma unroll
      for (int k=0;k<4;++k) mv[k] = ldMask(mask, base + j0 + k, fM);
    }
    float a4[4];
    if (fF){
      float4 av = *(const float4*)((const float*)adj + base + j0);
      a4[0]=av.x; a4[1]=av.y; a4[2]=av.z; a4[3]=av.w;
    } else {
      const UST* ap = (const UST*)adj + base + j0;
      #pragma unroll
      for (int k=0;k<4;++k) a4[k] = bf2f(ap[k]);
    }
    int my = (mv[0]&&mv[1]&&mv[2]&&mv[3]) ? 1 : 0;
    int wa = __all(my);
    int w = t >> 6;
    if ((t & 63) == 0) sAll[w] = wa;
    __syncthreads();
    int rowAll = sAll[0] & sAll[1] & sAll[2] & sAll[3];
    float es = expf(ldF(lsp, 0, fF));
    UST o4[4];
    #pragma unroll
    for (int k = 0; k < 4; ++k){
      int j = j0 + k;
      float av = fminf(fmaxf(a4[k], 0.f), 1.f);
      bool eff = mv[k] && !((rowAll != 0) && (j == i));
      o4[k] = f2bf(((eff ? -10000.f : 0.f) + es * av) * 1.44269504f);
    }
    *(int2*)&sTile[j0] = *(const int2*)o4;
    __syncthreads();
    // transpose-gather into attn fragment order
    int kt = t >> 4, l15 = t & 15;
    UST g4[4];
    #pragma unroll
    for (int ni=0; ni<4; ++ni) g4[ni] = sTile[kt*64 + ni*16 + l15];
    int b = row >> 10, rr = row & 1023;
    int qt = rr >> 6, q = rr & 63;
    int w2 = q >> 4, qd = (q >> 2) & 3, r = q & 3;
    long dst = ((long)((b*16 + qt)*16 + kt))*4096 + w2*1024 + (qd*16 + l15)*16 + r*4;
    *(int2*)(biasOut + dst) = *(const int2*)g4;
  } else {
    int cb = bid - BB*LL;
    int ti = cb >> 9, xi = cb & 511;
    int n = a.n[ti];
    long i8 = ((long)xi*256 + t)*8;
    if (i8 >= n) return;
    const void* s = a.src[ti]; UST* d = a.dst[ti];
    if (fF){
      const float4* sf = (const float4*)s;
      float4 a0 = sf[i8>>2], a1 = sf[(i8>>2)+1];
      UST o[8] = { f2bf(a0.x),f2bf(a0.y),f2bf(a0.z),f2bf(a0.w),
                   f2bf(a1.x),f2bf(a1.y),f2bf(a1.z),f2bf(a1.w) };
      *(int4*)(d+i8) = *(const int4*)o;
    } else {
      ((int4*)d)[i8>>3] = ((const int4*)s)[i8>>3];
    }
  }
}

// ---------------- MFMA GEMM: tile TM x TN, BK=64, dbuf prefetch ----------------
// Chunk-transposed LDS (0 bank conflicts): (R,C) at (R>>3)*512+(C>>3)*64+(R&7)*8+(C&7).
template<int TM, int TN, int ACT, int RES, int OUTMODE>
__global__ __launch_bounds__(256) void gemm3_k(const int* flags,
    const UST* __restrict__ A, const UST* __restrict__ Bw, const UST* __restrict__ bias,
    const float* __restrict__ resid, void* Cout, int M, int N, int K, int Ks){
  constexpr int MI = TM/32, NI = TN/32;
  __shared__ UST sA[2][TM*64];
  __shared__ UST sB[2][TN*64];
  int t = threadIdx.x, w = t>>6, lane = t&63, l15 = lane&15, qd = lane>>4;
  int m0 = blockIdx.x*TM, n0 = blockIdx.y*TN;
  int zoff = blockIdx.z * Ks;
  int wm = (w&1)*(TM/2), wn = (w>>1)*(TN/2);
  f32x4 acc[MI][NI];
  #pragma unroll
  for (int mi=0; mi<MI; ++mi)
    #pragma unroll
    for (int ni=0; ni<NI; ++ni){ acc[mi][ni][0]=0;acc[mi][ni][1]=0;acc[mi][ni][2]=0;acc[mi][ni][3]=0; }
  int sRow = lane&7, sCol = (lane>>3)*8;
  const UST* aS = A + (long)(m0 + w*(TM/4) + sRow)*K + sCol + zoff;
  const UST* bS = Bw + (long)(n0 + w*(TN/4) + sRow)*K + sCol + zoff;
  auto stage = [&](int buf, int k0){
    #pragma unroll
    for (int c=0;c<MI;++c) gld16(aS + (long)c*8*K + k0, (char*)&sA[buf][(w*(TM/4)+c*8)*64]);
    #pragma unroll
    for (int c=0;c<NI;++c) gld16(bS + (long)c*8*K + k0, (char*)&sB[buf][(w*(TN/4)+c*8)*64]);
  };
  stage(0, 0);
  for (int k0 = 0; k0 < Ks; k0 += 64){
    int cur = (k0>>6)&1, nxt = cur^1;
    __syncthreads();
    if (k0 + 64 < Ks) stage(nxt, k0+64);
    #pragma unroll
    for (int ks=0; ks<2; ++ks){
      bf16x8 afr[MI], bfr[NI];
      #pragma unroll
      for (int mi=0; mi<MI; ++mi){
        int R = wm + mi*16 + l15;
        afr[mi] = *(const bf16x8*)&sA[cur][(R>>3)*512 + (ks*4+qd)*64 + (R&7)*8];
      }
      #pragma unroll
      for (int ni=0; ni<NI; ++ni){
        int R = wn + ni*16 + l15;
        bfr[ni] = *(const bf16x8*)&sB[cur][(R>>3)*512 + (ks*4+qd)*64 + (R&7)*8];
      }
      #pragma unroll
      for (int mi=0; mi<MI; ++mi)
        #pragma unroll
        for (int ni=0; ni<NI; ++ni)
          acc[mi][ni] = mfma16(afr[mi], bfr[ni], acc[mi][ni]);
    }
  }
  if (OUTMODE == 3){
    float* P = (float*)Cout + (size_t)blockIdx.z * M * N;
    #pragma unroll
    for (int mi=0; mi<MI; ++mi)
      #pragma unroll
      for (int ni=0; ni<NI; ++ni){
        int gc = n0 + wn + ni*16 + l15;
        #pragma unroll
        for (int r=0; r<4; ++r){
          int grow = m0 + wm + mi*16 + qd*4 + r;
          P[(long)grow*N + gc] = acc[mi][ni][r];
        }
      }
    return;
  }
  int outF32 = (OUTMODE==1) || (OUTMODE==2 && flags[0]);
  #pragma unroll
  for (int mi=0; mi<MI; ++mi){
    #pragma unroll
    for (int ni=0; ni<NI; ++ni){
      int gc = n0 + wn + ni*16 + l15;
      float bv = bf2f(bias[gc]);
      #pragma unroll
      for (int r=0; r<4; ++r){
        int grow = m0 + wm + mi*16 + qd*4 + r;
        float c = acc[mi][ni][r] + bv;
        if (ACT) c = 0.5f*c*(1.f+erff(c*0.70710678118654752f));
        long oi = (long)grow*N + gc;
        if (RES) c += resid[oi];
        if (outF32) ((float*)Cout)[oi] = c;
        else ((UST*)Cout)[oi] = f2bf(c);
      }
    }
  }
}

// ---------------- split-K reduce: out = sum(parts) + bias + resid ----------------
__global__ __launch_bounds__(256) void reduce4_k(const int* flags,
    const float* __restrict__ parts, const UST* __restrict__ bias,
    const float* __restrict__ resid, void* __restrict__ dout){
  const long S = (long)NT*DD;
  long e = ((long)blockIdx.x*256 + threadIdx.x)*4;
  float4 a = *(const float4*)(parts + e);
  float4 b = *(const float4*)(parts + S + e);
  float4 c = *(const float4*)(parts + 2*S + e);
  float4 d = *(const float4*)(parts + 3*S + e);
  float4 r = *(const float4*)(resid + e);
  int gc = (int)(e & (DD-1));
  float v[4] = { a.x+b.x+c.x+d.x + bf2f(bias[gc+0]) + r.x,
                 a.y+b.y+c.y+d.y + bf2f(bias[gc+1]) + r.y,
                 a.z+b.z+c.z+d.z + bf2f(bias[gc+2]) + r.z,
                 a.w+b.w+c.w+d.w + bf2f(bias[gc+3]) + r.w };
  if (flags[0]){
    *(float4*)((float*)dout + e) = *(const float4*)v;
  } else {
    UST o4[4] = { f2bf(v[0]), f2bf(v[1]), f2bf(v[2]), f2bf(v[3]) };
    *(int2*)((UST*)dout + e) = *(const int2*)o4;
  }
}

// ---------------- LayerNorm row kernel: fp32 in -> bf16 out ----------------
__global__ __launch_bounds__(256) void ln_k(const int* flags, const float* xin,
    const void* gp, const void* bp, UST* xout){
  int fF = flags[0];
  int row = blockIdx.x, t = threadIdx.x;
  const float* xr = xin + (long)row * DD;
  float v0 = xr[t], v1 = xr[t+256];
  float s = v0+v1, q = v0*v0 + v1*v1;
  #pragma unroll
  for (int off=1; off<64; off<<=1){ s += __shfl_xor(s,off,64); q += __shfl_xor(q,off,64); }
  __shared__ float rs[4], rq[4];
  int w = t>>6;
  if ((t&63)==0){ rs[w]=s; rq[w]=q; }
  __syncthreads();
  float S = rs[0]+rs[1]+rs[2]+rs[3];
  float Q = rq[0]+rq[1]+rq[2]+rq[3];
  float mean = S * (1.f/DD);
  float var  = fmaxf(Q * (1.f/DD) - mean*mean, 0.f);
  float ri = rsqrtf(var + 1e-5f);
  float g0 = ldF(gp, t, fF), b0 = ldF(bp, t, fF);
  float g1 = ldF(gp, t+256, fF), b1 = ldF(bp, t+256, fF);
  xout[(long)row*DD + t]     = f2bf((v0-mean)*ri*g0 + b0);
  xout[(long)row*DD + t+256] = f2bf((v1-mean)*ri*g1 + b1);
}

// ---------------- V transpose: qkv -> vT[b,h,d,token] ----------------
__global__ __launch_bounds__(256) void repack_v(const UST* __restrict__ qkv, UST* __restrict__ vT){
  int id = blockIdx.x;
  int bh = id & 31, qt = id >> 5;
  int b = bh >> 3, h = bh & 7;
  int t = threadIdx.x, w = t >> 6, lane = t & 63;
  int token = qt*64 + lane;
  const UST* src = qkv + ((long)(b*LL + token))*1536 + 1024 + h*64;
  #pragma unroll
  for (int c = 0; c < 2; ++c){
    int ch = w*2 + c;
    union { int4 v; UST u[8]; } uu;
    uu.v = *(const int4*)(src + ch*8);
    #pragma unroll
    for (int i = 0; i < 8; ++i)
      vT[((long)(bh*64 + ch*8 + i))*LL + token] = uu.u[i];
  }
}

// ---------------- flash attention: no-max softmax, bias in registers, no split ----
// grid 512: id = qt*32 + h*4 + b (XCD-local per (b,h)).
__global__ __launch_bounds__(256) void attn_k(const UST* __restrict__ qkv,
    const UST* __restrict__ vT, const UST* __restrict__ bias2, UST* __restrict__ ctx){
  int id = blockIdx.x;
  int b = id & 3, h = (id>>2) & 7, qt = id >> 5;
  int bh = b*HH + h;
  int q0 = qt*64;
  int t = threadIdx.x, w = t>>6, lane = t&63, l15 = lane&15, qd = lane>>4;
  __shared__ UST sK[2][2][64*32];
  __shared__ UST sV[2][2][64*32];
  __shared__ UST sP[4][16*72];
  UST* myP = &sP[w][0];

  const UST* qrow = qkv + ((long)(b*LL + q0 + w*16 + l15))*1536 + h*64;
  bf16x8 qf0 = *(const bf16x8*)(qrow + qd*8);
  bf16x8 qf1 = *(const bf16x8*)(qrow + 32 + qd*8);

  const UST* kS = qkv + (long)(b*LL + w*16 + (lane&15))*1536 + 512 + h*64 + (lane>>4)*8;
  const UST* vS = vT + (long)(bh*64 + w*16 + (lane&15))*LL + (lane>>4)*8;
  const UST* bP = bias2 + ((long)((b*16 + qt)*16))*4096 + w*1024 + lane*16;

  f32x4 o[4]; float lsum[4];
  #pragma unroll
  for (int i=0;i<4;i++){ o[i][0]=0;o[i][1]=0;o[i][2]=0;o[i][3]=0; lsum[i]=0.f; }
  const float C1 = 0.18033688f;   // 0.125*log2e; bias pre-scaled by log2e

  auto stage = [&](int buf, int k0){
    gld16(kS + (long)k0*1536,      (char*)sK[buf][0] + w*1024);
    gld16(kS + (long)k0*1536 + 32, (char*)sK[buf][1] + w*1024);
    gld16(vS + k0,                 (char*)sV[buf][0] + w*1024);
    gld16(vS + k0 + 32,            (char*)sV[buf][1] + w*1024);
  };
  stage(0, 0);
  int4 bc0 = *(const int4*)(bP);
  int4 bc1 = *(const int4*)(bP + 8);

  for (int kt = 0; kt < 16; ++kt){
    int cur = kt&1, nxt = cur^1;
    int k0 = kt*64;
    __syncthreads();
    if (kt < 15) stage(nxt, k0+64);
    int kn = (kt < 15 ? kt+1 : 15);
    int4 bn0 = *(const int4*)(bP + (long)kn*4096);
    int4 bn1 = *(const int4*)(bP + (long)kn*4096 + 8);
    f32x4 s4[4];
    #pragma unroll
    for (int i=0;i<4;i++){ s4[i][0]=0;s4[i][1]=0;s4[i][2]=0;s4[i][3]=0; }
    #pragma unroll
    for (int ni=0; ni<4; ++ni){
      bf16x8 kf0 = *(const bf16x8*)&sK[cur][0][ni*512 + qd*128 + l15*8];
      bf16x8 kf1 = *(const bf16x8*)&sK[cur][1][ni*512 + qd*128 + l15*8];
      s4[ni] = mfma16(qf0, kf0, s4[ni]);
      s4[ni] = mfma16(qf1, kf1, s4[ni]);
    }
    union { int4 v; UST u[8]; } B0, B1;
    B0.v = bc0; B1.v = bc1;
    float p[4][4];
    #pragma unroll
    for (int ni=0; ni<4; ++ni){
      #pragma unroll
      for (int r=0; r<4; ++r){
        UST bu = (r < 2) ? B0.u[r*4 + ni] : B1.u[(r&1)*4 + ni];
        p[ni][r] = exp2f(fmaf(s4[ni][r], C1, bf2f(bu)));
      }
    }
    bc0 = bn0; bc1 = bn1;
    #pragma unroll
    for (int r=0; r<4; ++r)
      lsum[r] += (p[0][r]+p[1][r]) + (p[2][r]+p[3][r]);
    #pragma unroll
    for (int ni=0; ni<4; ++ni)
      #pragma unroll
      for (int r=0; r<4; ++r) myP[(qd*4+r)*72 + ni*16 + l15] = f2bf(p[ni][r]);
    bf16x8 pf0 = *(const bf16x8*)&myP[l15*72 + qd*8];
    bf16x8 pf1 = *(const bf16x8*)&myP[l15*72 + 32 + qd*8];
    #pragma unroll
    for (int dn=0; dn<4; ++dn){
      bf16x8 vf0 = *(const bf16x8*)&sV[cur][0][dn*512 + qd*128 + l15*8];
      bf16x8 vf1 = *(const bf16x8*)&sV[cur][1][dn*512 + qd*128 + l15*8];
      o[dn] = mfma16(pf0, vf0, o[dn]);
      o[dn] = mfma16(pf1, vf1, o[dn]);
    }
  }
  float linv[4];
  #pragma unroll
  for (int r=0; r<4; ++r){
    float s = lsum[r];
    #pragma unroll
    for (int off=1; off<16; off<<=1) s += __shfl_xor(s, off, 64);
    linv[r] = 1.f / s;
  }
  #pragma unroll
  for (int dn=0; dn<4; ++dn){
    #pragma unroll
    for (int r=0; r<4; ++r){
      long oi = ((long)(b*LL + q0 + w*16 + qd*4 + r))*DD + h*64 + dn*16 + l15;
      ctx[oi] = f2bf(o[dn][r] * linv[r]);
    }
  }
}

extern "C" void kernel_launch(void* const* d_in, const int* in_sizes, int n_in,
                              void* d_out, int out_size, void* d_ws, size_t ws_size,
                              hipStream_t stream){
  char* ws = (char*)d_ws;
  size_t o = 0;
  auto alloc = [&](size_t b){ size_t r = o; o += (b + 255) & ~(size_t)255; return r; };
  int*   flags = (int*)(ws + alloc(256));
  size_t biasOff = alloc(8UL<<20);
  size_t qkvOff  = alloc(12UL<<20);
  UST* biasC = (UST*)(ws + biasOff);
  UST* qkv   = (UST*)(ws + qkvOff);
  UST* hb    = (UST*)(ws + biasOff);        // aliases biasC+qkv (dead by ffn1)
  UST* vT    = (UST*)(ws + alloc(4UL<<20));
  UST* xbf   = (UST*)(ws + alloc(2UL<<20));
  UST* wfuse = (UST*)(ws + alloc(131072*2));
  UST* bfuse = (UST*)(ws + alloc(1024));
  UST* ipw   = (UST*)(ws + alloc(786432*2));
  UST* ipb   = (UST*)(ws + alloc(3072*2));
  UST* outw  = (UST*)(ws + alloc(262144*2));
  UST* outb  = (UST*)(ws + alloc(1024));
  UST* w1    = (UST*)(ws + alloc(1048576*2));
  UST* b1    = (UST*)(ws + alloc(4096*2));
  UST* w2    = (UST*)(ws + alloc(1048576*2));
  UST* b2    = (UST*)(ws + alloc(1024));
  float* xf  = (float*)(ws + alloc((size_t)NT*DD*4));
  UST* xn    = (UST*)(ws + alloc((size_t)NT*DD*2));
  UST* ctx   = (UST*)(ws + alloc((size_t)NT*DD*2));
  float* x2  = (float*)(ws + alloc((size_t)NT*DD*4));
  size_t partsOff = alloc(4UL*NT*DD*4);     // 33.5MB ffn2 split-K partials
  float* parts = (float*)(ws + partsOff);
  bool doSplit = (o <= ws_size);

  CvtArgs ca;
  const int srcIdx[11] = {0,3,4,5,6,7,8,13,14,15,16};
  UST* dsts[11] = {xbf,wfuse,bfuse,ipw,ipb,outw,outb,w1,b1,w2,b2};
  const int ns[11] = {NT*IND, DD*IND, DD, 3*DD*DD, 3*DD, DD*DD, DD, FFD*DD, FFD, DD*FFD, DD};
  for (int i=0;i<11;i++){ ca.src[i]=d_in[srcIdx[i]]; ca.dst[i]=dsts[i]; ca.n[i]=ns[i]; }
  prep_k<<<BB*LL + 11*512, 256, 0, stream>>>(flags, ca, (const UST*)d_in[0],
                                             d_in[1], d_in[2], d_in[17], biasC);

  gemm3_k<64,64,0,0,1><<<dim3(64,8), 256, 0, stream>>>(flags, xbf, wfuse, bfuse, nullptr, xf, NT, DD, IND, IND);
  ln_k<<<NT, 256, 0, stream>>>(flags, xf, d_in[9], d_in[10], xn);
  gemm3_k<64,128,0,0,0><<<dim3(64,12), 256, 0, stream>>>(flags, xn, ipw, ipb, nullptr, qkv, NT, 3*DD, DD, DD);
  repack_v<<<512, 256, 0, stream>>>(qkv, vT);
  attn_k<<<512, 256, 0, stream>>>(qkv, vT, biasC, ctx);
  gemm3_k<64,64,0,1,1><<<dim3(64,8), 256, 0, stream>>>(flags, ctx, outw, outb, xf, x2, NT, DD, DD, DD);
  ln_k<<<NT, 256, 0, stream>>>(flags, x2, d_in[11], d_in[12], xn);
  gemm3_k<128,128,1,0,0><<<dim3(32,16), 256, 0, stream>>>(flags, xn, w1, b1, nullptr, hb, NT, FFD, DD, DD);
  if (doSplit){
    gemm3_k<128,128,0,0,3><<<dim3(32,4,4), 256, 0, stream>>>(flags, hb, w2, b2, nullptr, parts, NT, DD, FFD, FFD/4);
    reduce4_k<<<(NT*DD)/1024, 256, 0, stream>>>(flags, parts, b2, x2, d_out);
  } else {
    gemm3_k<64,64,0,1,2><<<dim3(64,8), 256, 0, stream>>>(flags, hb, w2, b2, x2, d_out, NT, DD, FFD, FFD);
  }
}